// Round 2
// baseline (348.342 us; speedup 1.0000x reference)
//
#include <hip/hip_runtime.h>
#include <stdint.h>

// Fused causal linear attention: out[b,h,i,d] = sum_{j<=i} (q_i . k_j) * v_j[d]
// B=4 H=16 T=2048 D=128, fp32 in/out. One kernel: per-(b,h) chunked scan with
// the running state S[d'][d] held in MFMA accumulators, D split 8-ways across
// blocks so grid = 64*8 = 512 (2 blocks/CU).
#define BATCH  4
#define HEADS  16
#define SEQ    2048
#define DIM    128
#define CHUNK  128
#define NCHUNK 16
#define NBH    64
#define DSPLIT 8
#define DCOLS  16          // DIM / DSPLIT

typedef __attribute__((ext_vector_type(8))) short short8;   // 8 bf16
typedef __attribute__((ext_vector_type(4))) float floatx4;  // MFMA acc

#define MFMA(a, b, c) __builtin_amdgcn_mfma_f32_16x16x32_bf16((a), (b), (c), 0, 0, 0)

__device__ __forceinline__ short f2bf(float f) {
  union { float f; uint32_t u; } x; x.f = f;
  uint32_t r = x.u + 0x7fffu + ((x.u >> 16) & 1u);   // RNE
  return (short)(r >> 16);
}

// Wave w (of 8) owns out rows [16w,16w+16) of each chunk and state-slice
// n-tile w (state cols d' in [16w,16w+16), all 16 slice d-rows).
__global__ __launch_bounds__(512, 4) void k_fused(
    const float* __restrict__ qin, const float* __restrict__ kin,
    const float* __restrict__ vin, float* __restrict__ out) {
  const int blk = blockIdx.x;
  const int bh  = blk >> 3;              // 64 heads
  const int dsl = blk & 7;               // D slice
  const int ds0 = dsl * DCOLS;
  const size_t hb = (size_t)bh * SEQ * DIM;
  const float* qb = qin + hb;
  const float* kb = kin + hb;
  const float* vb = vin + hb;
  float* ob = out + hb;

  // strides: 136 shorts = 272 B (16B-aligned rows); Ps 72 shorts = 144 B.
  __shared__ short Klds[128][136];  // K chunk, bf16 row-major
  __shared__ short Vt[16][136];     // V slice transposed: Vt[d][j]
  __shared__ short Stl[16][136];    // pre-chunk state transposed: Stl[d][d']
  __shared__ short Ps[128][72];     // masked P, per-wave rows, 64-col halves

  const int tid  = threadIdx.x;
  const int wave = tid >> 6;
  const int lane = tid & 63;
  const int q4   = lane >> 4;
  const int l16  = lane & 15;

  // persistent state accumulator: St[d=q4*4+r][d'=16*wave+l16], fp32
  floatx4 stacc;
#pragma unroll
  for (int r = 0; r < 4; ++r) stacc[r] = 0.f;

  for (int c = 0; c < NCHUNK; ++c) {
    const float* kc = kb + (size_t)c * CHUNK * DIM;
    const float* vc = vb + (size_t)c * CHUNK * DIM;
    const float* qc = qb + (size_t)c * CHUNK * DIM;
    float* oc = ob + (size_t)c * CHUNK * DIM;

    // Q A-fragments for this chunk: issue global loads before the barrier so
    // they overlap the staging stores. A[m=row][k=d'], rows 16w..16w+15.
    float4 qx[4][2];
    {
      const float* qrow = qc + (size_t)(wave * 16 + l16) * DIM + q4 * 8;
#pragma unroll
      for (int ks = 0; ks < 4; ++ks) {
        qx[ks][0] = *(const float4*)(qrow + ks * 32);
        qx[ks][1] = *(const float4*)(qrow + ks * 32 + 4);
      }
    }

    __syncthreads();   // previous chunk's LDS reads are done

    // ---- stage K chunk (128x128 fp32 -> bf16 row-major) ----
#pragma unroll
    for (int it = 0; it < 4; ++it) {
      const int e = it * 4096 + tid * 8;
      const int row = e >> 7, col = e & 127;
      const float4 x0 = *(const float4*)(kc + e);
      const float4 x1 = *(const float4*)(kc + e + 4);
      short8 s;
      s[0] = f2bf(x0.x); s[1] = f2bf(x0.y); s[2] = f2bf(x0.z); s[3] = f2bf(x0.w);
      s[4] = f2bf(x1.x); s[5] = f2bf(x1.y); s[6] = f2bf(x1.z); s[7] = f2bf(x1.w);
      *(short8*)&Klds[row][col] = s;
    }
    // ---- stage V slice transposed: Vt[d][j] (128 j x 16 d) ----
    {
      const int e = tid * 4;
      const int j = e >> 4, d = e & 15;
      const float4 xv = *(const float4*)(vc + (size_t)j * DIM + ds0 + d);
      Vt[d + 0][j] = f2bf(xv.x);
      Vt[d + 1][j] = f2bf(xv.y);
      Vt[d + 2][j] = f2bf(xv.z);
      Vt[d + 3][j] = f2bf(xv.w);
    }
    // ---- dump pre-chunk state to LDS (C-layout -> Stl[d][d']) ----
#pragma unroll
    for (int r = 0; r < 4; ++r)
      Stl[q4 * 4 + r][wave * 16 + l16] = f2bf(stacc[r]);

    __syncthreads();

    // pack Q frags to bf16
    short8 aq[4];
#pragma unroll
    for (int ks = 0; ks < 4; ++ks) {
      short8 f;
      f[0] = f2bf(qx[ks][0].x); f[1] = f2bf(qx[ks][0].y);
      f[2] = f2bf(qx[ks][0].z); f[3] = f2bf(qx[ks][0].w);
      f[4] = f2bf(qx[ks][1].x); f[5] = f2bf(qx[ks][1].y);
      f[6] = f2bf(qx[ks][1].z); f[7] = f2bf(qx[ks][1].w);
      aq[ks] = f;
    }

    floatx4 oacc;
#pragma unroll
    for (int r = 0; r < 4; ++r) oacc[r] = 0.f;

    // ---- out += Q @ S_pre : B[k=d'][n=d] = Stl[d][d'] row-contiguous ----
#pragma unroll
    for (int ks = 0; ks < 4; ++ks) {
      const short8 bs = *(const short8*)&Stl[l16][ks * 32 + q4 * 8];
      oacc = MFMA(aq[ks], bs, oacc);
    }

    // ---- causal scores + P@V, in two 64-col halves (Ps reuse) ----
    for (int h = 0; h < 2; ++h) {
      if (4 * h > wave) break;           // wave-uniform: half not needed
      const int tn_hi = (wave < 4 * h + 3) ? wave : 4 * h + 3;
      for (int tn = 4 * h; tn <= tn_hi; ++tn) {
        floatx4 sacc;
#pragma unroll
        for (int r = 0; r < 4; ++r) sacc[r] = 0.f;
#pragma unroll
        for (int ks = 0; ks < 4; ++ks) {
          const short8 bk = *(const short8*)&Klds[tn * 16 + l16][ks * 32 + q4 * 8];
          sacc = MFMA(aq[ks], bk, sacc);
        }
        const int lc = (tn - 4 * h) * 16 + l16;
#pragma unroll
        for (int r = 0; r < 4; ++r) {
          float val = sacc[r];
          if (tn == wave && l16 > q4 * 4 + r) val = 0.f;  // diagonal mask
          Ps[wave * 16 + q4 * 4 + r][lc] = f2bf(val);
        }
      }
      // zero-pad tile tn = wave+1 if it lies in this half (read-range cover)
      if (wave + 1 <= 4 * h + 3 && wave + 1 >= 4 * h) {
        const int lc = (wave + 1 - 4 * h) * 16 + l16;
#pragma unroll
        for (int r = 0; r < 4; ++r) Ps[wave * 16 + q4 * 4 + r][lc] = 0;
      }
      // P@V for this half (A from own-wave Ps rows, B from Vt rows)
#pragma unroll
      for (int t = 0; t < 2; ++t) {
        if (64 * h + 32 * t <= 16 * wave + 15) {
          const short8 ap = *(const short8*)&Ps[wave * 16 + l16][t * 32 + q4 * 8];
          const short8 bv = *(const short8*)&Vt[l16][64 * h + t * 32 + q4 * 8];
          oacc = MFMA(ap, bv, oacc);
        }
      }
    }

    // ---- write out tile (C-layout -> global fp32) ----
#pragma unroll
    for (int r = 0; r < 4; ++r)
      oc[(size_t)(wave * 16 + q4 * 4 + r) * DIM + ds0 + l16] = oacc[r];

    // ---- state update: St[d][d'] += sum_j Vt[d][j] * K[j][d'] ----
#pragma unroll
    for (int ks = 0; ks < 4; ++ks) {
      const short8 av = *(const short8*)&Vt[l16][ks * 32 + q4 * 8];
      short8 bkc;                       // B[k=j][n=d'] = Klds[j][16w+l16]
#pragma unroll
      for (int r = 0; r < 8; ++r) bkc[r] = Klds[ks * 32 + q4 * 8 + r][wave * 16 + l16];
      stacc = MFMA(av, bkc, stacc);
    }
  }
}

// ---------------------------------------------------------------------------
extern "C" void kernel_launch(void* const* d_in, const int* in_sizes, int n_in,
                              void* d_out, int out_size, void* d_ws, size_t ws_size,
                              hipStream_t stream) {
  const float* q = (const float*)d_in[0];
  const float* k = (const float*)d_in[1];
  const float* v = (const float*)d_in[2];
  float* out = (float*)d_out;
  (void)d_ws; (void)ws_size; (void)in_sizes; (void)n_in; (void)out_size;

  hipLaunchKernelGGL(k_fused, dim3(NBH * DSPLIT), dim3(512), 0, stream,
                     q, k, v, out);
}

// Round 3
// 244.676 us; speedup vs baseline: 1.4237x; 1.4237x over previous
//
#include <hip/hip_runtime.h>
#include <stdint.h>

// Fused causal linear attention: out[b,h,i,d] = sum_{j<=i} (q_i . k_j) * v_j[d]
// B=4 H=16 T=2048 D=128, fp32 in/out. Single kernel: per-(b,h) chunked scan,
// running state in MFMA accumulators. D split 4-ways -> grid 64*4 = 256 blocks
// (1 block/CU on all CUs). Same-bh blocks mapped to one XCD for L2 dedup.
// Chunk loop software-pipelined: next chunk's Q/K/V prefetched into registers.
#define SEQ    2048
#define DIM    128
#define CHUNK  128
#define NCHUNK 16
#define NBH    64
#define DSPLIT 4
#define DCOLS  32          // DIM / DSPLIT

typedef __attribute__((ext_vector_type(8))) short short8;   // 8 bf16
typedef __attribute__((ext_vector_type(4))) float floatx4;  // MFMA acc

#define MFMA(a, b, c) __builtin_amdgcn_mfma_f32_16x16x32_bf16((a), (b), (c), 0, 0, 0)

__device__ __forceinline__ short f2bf(float f) {
  union { float f; uint32_t u; } x; x.f = f;
  uint32_t r = x.u + 0x7fffu + ((x.u >> 16) & 1u);   // RNE
  return (short)(r >> 16);
}
__device__ __forceinline__ short8 pack8(const float4 a, const float4 b) {
  short8 s;
  s[0] = f2bf(a.x); s[1] = f2bf(a.y); s[2] = f2bf(a.z); s[3] = f2bf(a.w);
  s[4] = f2bf(b.x); s[5] = f2bf(b.y); s[6] = f2bf(b.z); s[7] = f2bf(b.w);
  return s;
}

// Wave w (0..7): out i-tile w (rows 16w..16w+16) x 32 slice cols; causal score
// tiles tj<=w; state n-tile w (d' cols 16w..16w+16) x full 32 slice rows.
__global__ __launch_bounds__(512, 2) void k_fused(
    const float* __restrict__ qin, const float* __restrict__ kin,
    const float* __restrict__ vin, float* __restrict__ out) {
  const int blk = blockIdx.x;
  const int bh  = blk & 63;              // same-bh blocks share blk%8 -> XCD
  const int dsl = blk >> 6;              // D slice 0..3
  const int ds0 = dsl * DCOLS;
  const size_t hb = (size_t)bh * SEQ * DIM;
  const float* qb = qin + hb;
  const float* kb = kin + hb;
  const float* vb = vin + hb;
  float* ob = out + hb;

  __shared__ short Klds[128][136];  // K chunk bf16 row-major (16B-aligned rows)
  __shared__ short Vt[32][136];     // V slice transposed: Vt[d_loc][j]
  __shared__ short Stl[32][136];    // pre-chunk state: Stl[d_loc][d']
  __shared__ short Ps[128][136];    // masked P: Ps[i_loc][j]

  const int tid  = threadIdx.x;
  const int wave = tid >> 6;
  const int lane = tid & 63;
  const int q4   = lane >> 4;
  const int l16  = lane & 15;

  // persistent state: St[d_loc = 16mt + q4*4+r][d' = 16*wave + l16]
  floatx4 stacc[2];
#pragma unroll
  for (int mt = 0; mt < 2; ++mt)
#pragma unroll
    for (int r = 0; r < 4; ++r) stacc[mt][r] = 0.f;

  // prefetch registers
  float4 qx[4][2], kx[4][2], vx[2];
  const int vj = tid >> 3, vd0 = (tid & 7) * 4;

  auto load_chunk = [&](int c) {
    const float* qrow = qb + (size_t)c * CHUNK * DIM
                        + (size_t)(wave * 16 + l16) * DIM + q4 * 8;
#pragma unroll
    for (int ks = 0; ks < 4; ++ks) {
      qx[ks][0] = *(const float4*)(qrow + ks * 32);
      qx[ks][1] = *(const float4*)(qrow + ks * 32 + 4);
    }
    const float* kcp = kb + (size_t)c * CHUNK * DIM;
#pragma unroll
    for (int it = 0; it < 4; ++it) {
      const int e = it * 4096 + tid * 8;
      kx[it][0] = *(const float4*)(kcp + e);
      kx[it][1] = *(const float4*)(kcp + e + 4);
    }
    const float* vcp = vb + (size_t)c * CHUNK * DIM + ds0;
    vx[0] = *(const float4*)(vcp + (size_t)vj * DIM + vd0);
    vx[1] = *(const float4*)(vcp + (size_t)(vj + 64) * DIM + vd0);
  };

  load_chunk(0);

  for (int c = 0; c < NCHUNK; ++c) {
    __syncthreads();   // previous chunk's LDS reads complete

    // ---- stage prefetched K (row-major bf16, b128 stores) ----
#pragma unroll
    for (int it = 0; it < 4; ++it) {
      const int e = it * 4096 + tid * 8;
      *(short8*)&Klds[e >> 7][e & 127] = pack8(kx[it][0], kx[it][1]);
    }
    // ---- stage V slice transposed ----
    Vt[vd0 + 0][vj] = f2bf(vx[0].x);
    Vt[vd0 + 1][vj] = f2bf(vx[0].y);
    Vt[vd0 + 2][vj] = f2bf(vx[0].z);
    Vt[vd0 + 3][vj] = f2bf(vx[0].w);
    Vt[vd0 + 0][vj + 64] = f2bf(vx[1].x);
    Vt[vd0 + 1][vj + 64] = f2bf(vx[1].y);
    Vt[vd0 + 2][vj + 64] = f2bf(vx[1].z);
    Vt[vd0 + 3][vj + 64] = f2bf(vx[1].w);
    // ---- dump pre-chunk state (C-layout -> Stl[d_loc][d']) ----
#pragma unroll
    for (int mt = 0; mt < 2; ++mt)
#pragma unroll
      for (int r = 0; r < 4; ++r)
        Stl[mt * 16 + q4 * 4 + r][wave * 16 + l16] = f2bf(stacc[mt][r]);

    // pack Q A-frags before prefetch overwrites qx
    short8 aq[4];
#pragma unroll
    for (int ks = 0; ks < 4; ++ks) aq[ks] = pack8(qx[ks][0], qx[ks][1]);

    __syncthreads();

    if (c + 1 < NCHUNK) load_chunk(c + 1);   // in flight during compute

    // ---- out = Q @ S_pre : B[k=d'][n=d_loc] = Stl[d_loc][d'] rows ----
    floatx4 oacc[2];
#pragma unroll
    for (int tn = 0; tn < 2; ++tn)
#pragma unroll
      for (int r = 0; r < 4; ++r) oacc[tn][r] = 0.f;
#pragma unroll
    for (int ks = 0; ks < 4; ++ks)
#pragma unroll
      for (int tn = 0; tn < 2; ++tn) {
        const short8 bs = *(const short8*)&Stl[tn * 16 + l16][ks * 32 + q4 * 8];
        oacc[tn] = MFMA(aq[ks], bs, oacc[tn]);
      }

    // ---- causal scores for i-tile `wave`, j-tiles 0..wave ----
    for (int tj = 0; tj <= wave; ++tj) {
      floatx4 sacc;
#pragma unroll
      for (int r = 0; r < 4; ++r) sacc[r] = 0.f;
#pragma unroll
      for (int ks = 0; ks < 4; ++ks) {
        const short8 bk = *(const short8*)&Klds[tj * 16 + l16][ks * 32 + q4 * 8];
        sacc = MFMA(aq[ks], bk, sacc);
      }
#pragma unroll
      for (int r = 0; r < 4; ++r) {
        float val = sacc[r];
        if (tj == wave && l16 > q4 * 4 + r) val = 0.f;   // strict-upper mask
        Ps[wave * 16 + q4 * 4 + r][tj * 16 + l16] = f2bf(val);
      }
    }
    if ((wave & 1) == 0) {   // even wave: zero tile wave+1 (PV k-step pad)
#pragma unroll
      for (int r = 0; r < 4; ++r)
        Ps[wave * 16 + q4 * 4 + r][(wave + 1) * 16 + l16] = 0;
    }

    // ---- PV: same-wave Ps rows (no barrier needed) ----
    const int kst = (wave + 2) >> 1;
    for (int t = 0; t < kst; ++t) {
      const short8 ap = *(const short8*)&Ps[wave * 16 + l16][t * 32 + q4 * 8];
#pragma unroll
      for (int tn = 0; tn < 2; ++tn) {
        const short8 bv = *(const short8*)&Vt[tn * 16 + l16][t * 32 + q4 * 8];
        oacc[tn] = MFMA(ap, bv, oacc[tn]);
      }
    }

    // ---- write out tile ----
    float* oc = ob + (size_t)c * CHUNK * DIM;
#pragma unroll
    for (int tn = 0; tn < 2; ++tn)
#pragma unroll
      for (int r = 0; r < 4; ++r)
        oc[(size_t)(wave * 16 + q4 * 4 + r) * DIM + ds0 + tn * 16 + l16] =
            oacc[tn][r];

    // ---- state update: St[d_loc][d'] += sum_j Vt[d_loc][j] K[j][d'] ----
#pragma unroll
    for (int ks = 0; ks < 4; ++ks) {
      short8 bkc;                 // B[k=j][n=d'] = Klds[j][16*wave + l16]
#pragma unroll
      for (int r = 0; r < 8; ++r)
        bkc[r] = Klds[ks * 32 + q4 * 8 + r][wave * 16 + l16];
#pragma unroll
      for (int mt = 0; mt < 2; ++mt) {
        const short8 av = *(const short8*)&Vt[mt * 16 + l16][ks * 32 + q4 * 8];
        stacc[mt] = MFMA(av, bkc, stacc[mt]);
      }
    }
  }
}

// ---------------------------------------------------------------------------
extern "C" void kernel_launch(void* const* d_in, const int* in_sizes, int n_in,
                              void* d_out, int out_size, void* d_ws, size_t ws_size,
                              hipStream_t stream) {
  const float* q = (const float*)d_in[0];
  const float* k = (const float*)d_in[1];
  const float* v = (const float*)d_in[2];
  float* out = (float*)d_out;
  (void)d_ws; (void)ws_size; (void)in_sizes; (void)n_in; (void)out_size;

  hipLaunchKernelGGL(k_fused, dim3(NBH * DSPLIT), dim3(512), 0, stream,
                     q, k, v, out);
}